// Round 4
// baseline (1464.475 us; speedup 1.0000x reference)
//
#include <hip/hip_runtime.h>
#include <hip/hip_bf16.h>

// SimVQ: z[16,1024,64] f32, codebook[16384,64] f32, proj_w[64,64] f32, proj_b[64] f32, scale f32
// Outputs (fp32, concat): quantized_st[1048576], vq_loss[1], idx[16384]
// Dtype model (pinned by round-3 absmax 16384.26 == bf16-idx-as-high-u16-of-fp32):
//   inputs fp32, outputs fp32. Scratch in __device__ globals (ws_size < 13MB crashed r1/r2).
// Argmax must match np ref EXACTLY (threshold 327.68 vs idx range 16383): fp32 GEMM with
// top-2 margin, fp64 re-check of near-ties (gap < 1e-4) against fp64 codebook.

#define NCODES 16384
#define NTOK   16384
#define DIM    64
#define MARGIN 1e-4f

__device__ float  g_qcb[NCODES * DIM];    // 4 MB  projected codebook fp32 (rounded from fp64)
__device__ float  g_cnT[DIM * NCODES];    // 4 MB  l2norm(qcb) transposed [d][n] fp32
__device__ double g_cn64[NCODES * DIM];   // 8 MB  l2norm(qcb) fp64 row-major (recheck path)
__device__ float  g_znT[DIM * NTOK];      // 4 MB  l2norm(z) transposed [d][t] fp32
__device__ float  g_bestv[4 * NTOK];      // per-split top-1 value
__device__ float  g_secv[4 * NTOK];       // per-split top-2 value
__device__ int    g_bidx[4 * NTOK];       // per-split top-1 idx
__device__ int    g_idx[NTOK];            // final idx
__device__ int    g_flagcnt;
__device__ int    g_flaglist[NTOK];
__device__ float  g_loss;

__device__ __forceinline__ float wave_sum64(float v) {
#pragma unroll
  for (int o = 32; o > 0; o >>= 1) v += __shfl_xor(v, o, 64);
  return v;
}
__device__ __forceinline__ double wave_sum64d(double v) {
#pragma unroll
  for (int o = 32; o > 0; o >>= 1) v += __shfl_xor(v, o, 64);
  return v;
}

// Kernel A: qcb = cb @ W^T + b in fp64 (near-exact); emit fp32 qcb, fp32 cnT, fp64 cn64.
__global__ __launch_bounds__(256) void k_codebook(const float* __restrict__ cb,
                                                  const float* __restrict__ pw,
                                                  const float* __restrict__ pb) {
  __shared__ float Wt[64 * 65];  // Wt[k][j] = W[j][k]
  __shared__ float cl[64 * 65];  // fp32 cn rows staged for transpose
  int tid = threadIdx.x;
  int base = blockIdx.x * 64;
  for (int e = tid; e < 4096; e += 256) {
    int j = e >> 6, k = e & 63;
    Wt[k * 65 + j] = pw[e];
  }
  __syncthreads();
  int w = tid >> 6, j = tid & 63;
  double bj = (double)pb[j];
  for (int r = 0; r < 16; ++r) {
    int nl = w * 16 + r;
    int n = base + nl;
    float cbv = cb[(size_t)n * 64 + j];
    double acc = bj;
#pragma unroll
    for (int k = 0; k < 64; ++k)
      acc = fma((double)__shfl(cbv, k, 64), (double)Wt[k * 65 + j], acc);
    g_qcb[(size_t)n * 64 + j] = (float)acc;
    double tot = wave_sum64d(acc * acc);
    double cn = acc / fmax(sqrt(tot), 1e-12);
    g_cn64[(size_t)n * 64 + j] = cn;
    cl[nl * 65 + j] = (float)cn;
  }
  __syncthreads();
  for (int e = tid; e < 4096; e += 256) {
    int d = e >> 6, r = e & 63;
    g_cnT[(size_t)d * NCODES + base + r] = cl[r * 65 + d];
  }
}

// Kernel B: znT[d][token] = l2norm(z rows); re-zeros g_flagcnt / g_loss each call
__global__ __launch_bounds__(256) void k_znorm(const float* __restrict__ z) {
  __shared__ float zl[64 * 65];
  int tid = threadIdx.x;
  int base = blockIdx.x * 64;
  if (blockIdx.x == 0 && tid == 0) { g_loss = 0.0f; g_flagcnt = 0; }
  int w = tid >> 6, j = tid & 63;
  for (int r = 0; r < 16; ++r) {
    int nl = w * 16 + r;
    int b = base + nl;
    float v = z[(size_t)b * 64 + j];
    float tot = wave_sum64(v * v);
    zl[nl * 65 + j] = v / fmaxf(sqrtf(tot), 1e-12f);
  }
  __syncthreads();
  for (int e = tid; e < 4096; e += 256) {
    int d = e >> 6, r = e & 63;
    g_znT[(size_t)d * NTOK + base + r] = zl[r * 65 + d];
  }
}

// Kernel C: fp32 GEMM (zn · cn^T) + per-token top-2 over this code-split.
// Grid = 256 token-blocks x 4 code-splits; block owns (tokBlock, split) exclusively.
__global__ __launch_bounds__(256) void k_argmax() {
  __shared__ float Zs[64 * 64];  // [d][tok]
  __shared__ float Cs[64 * 64];  // [d][code]
  __shared__ float rV[64 * 16];
  __shared__ float rS[64 * 16];
  __shared__ int rI[64 * 16];
  int tid = threadIdx.x;
  int bx = blockIdx.x;
  int split = bx & 3;
  int tokBase = (bx >> 2) * 64;
  int code0 = split * 4096;

  for (int f = tid; f < 1024; f += 256) {
    int d = f >> 4, p = f & 15;
    float4 v = *(const float4*)(g_znT + (size_t)d * NTOK + tokBase + p * 4);
    *(float4*)(Zs + d * 64 + p * 4) = v;
  }
  int tx = tid & 15, ty = tid >> 4;
  float bv[4], sv[4];
  int bi[4];
#pragma unroll
  for (int i = 0; i < 4; ++i) { bv[i] = -3.0e38f; sv[i] = -3.0e38f; bi[i] = 0; }

  for (int t = 0; t < 64; ++t) {
    int codeBase = code0 + t * 64;
    for (int f = tid; f < 1024; f += 256) {
      int d = f >> 4, p = f & 15;
      float4 v = *(const float4*)(g_cnT + (size_t)d * NCODES + codeBase + p * 4);
      *(float4*)(Cs + d * 64 + p * 4) = v;
    }
    __syncthreads();  // covers Zs on first iteration too

    float acc[4][4];
#pragma unroll
    for (int i = 0; i < 4; ++i)
#pragma unroll
      for (int jj = 0; jj < 4; ++jj) acc[i][jj] = 0.0f;

#pragma unroll 8
    for (int d = 0; d < 64; ++d) {
      float4 a = *(const float4*)(Zs + d * 64 + ty * 4);
      float4 b = *(const float4*)(Cs + d * 64 + tx * 4);
      float av[4] = {a.x, a.y, a.z, a.w};
      float bw[4] = {b.x, b.y, b.z, b.w};
#pragma unroll
      for (int i = 0; i < 4; ++i)
#pragma unroll
        for (int jj = 0; jj < 4; ++jj)
          acc[i][jj] = fmaf(av[i], bw[jj], acc[i][jj]);
    }
    // top-2 update; candidates ascend in code index per thread -> first-occurrence kept
#pragma unroll
    for (int i = 0; i < 4; ++i)
#pragma unroll
      for (int jj = 0; jj < 4; ++jj) {
        float v = acc[i][jj];
        if (v > bv[i]) { sv[i] = bv[i]; bv[i] = v; bi[i] = codeBase + tx * 4 + jj; }
        else if (v > sv[i]) sv[i] = v;  // v == bv lands here -> sv = bv -> gap 0 -> flagged
      }
    __syncthreads();
  }

#pragma unroll
  for (int i = 0; i < 4; ++i) {
    rV[(ty * 4 + i) * 16 + tx] = bv[i];
    rS[(ty * 4 + i) * 16 + tx] = sv[i];
    rI[(ty * 4 + i) * 16 + tx] = bi[i];
  }
  __syncthreads();
  if (tid < 64) {
    float B = rV[tid * 16], S = rS[tid * 16];
    int I = rI[tid * 16];
    for (int x = 1; x < 16; ++x) {
      float b = rV[tid * 16 + x], s2 = rS[tid * 16 + x];
      int i = rI[tid * 16 + x];
      if (b > B) { S = fmaxf(B, s2); B = b; I = i; }
      else if (b == B) { if (i < I) I = i; S = B; }
      else S = fmaxf(S, b);
    }
    g_bestv[split * NTOK + tokBase + tid] = B;
    g_secv[split * NTOK + tokBase + tid] = S;
    g_bidx[split * NTOK + tokBase + tid] = I;
  }
}

// Kernel D: merge 4 splits per token; flag near-ties for fp64 recheck
__global__ __launch_bounds__(256) void k_combine() {
  int tok = blockIdx.x * 256 + threadIdx.x;
  float B = -3.0e38f, S = -3.0e38f;
  int I = 0;
  for (int s = 0; s < 4; ++s) {
    float b = g_bestv[s * NTOK + tok], s2 = g_secv[s * NTOK + tok];
    int i = g_bidx[s * NTOK + tok];
    if (b > B) { S = fmaxf(B, s2); B = b; I = i; }
    else if (b == B) { if (i < I) I = i; S = B; }
    else S = fmaxf(S, b);
  }
  g_idx[tok] = I;
  if (B - S < MARGIN) {
    int p = atomicAdd(&g_flagcnt, 1);
    g_flaglist[p] = tok;
  }
}

// Kernel E: exact fp64 re-argmax for flagged tokens
__global__ __launch_bounds__(256) void k_recheck(const float* __restrict__ z) {
  __shared__ double zn[64];
  __shared__ double rb[256];
  __shared__ int ri[256];
  int tid = threadIdx.x;
  int cnt = g_flagcnt;
  for (int f = blockIdx.x; f < cnt; f += gridDim.x) {
    int tok = g_flaglist[f];
    if (tid < 64) {
      double v = (double)z[(size_t)tok * 64 + tid];
      double tot = wave_sum64d(v * v);
      zn[tid] = v / fmax(sqrt(tot), 1e-12);
    }
    __syncthreads();
    double best = -1.0e300;
    int bidx = 0x7FFFFFFF;
    for (int c = tid; c < NCODES; c += 256) {
      const double* cr = &g_cn64[(size_t)c * 64];
      double d = 0.0;
#pragma unroll 16
      for (int k = 0; k < 64; ++k) d = fma(zn[k], cr[k], d);
      if (d > best || (d == best && c < bidx)) { best = d; bidx = c; }
    }
    rb[tid] = best;
    ri[tid] = bidx;
    __syncthreads();
    if (tid == 0) {
      double B = rb[0];
      int I = ri[0];
      for (int x = 1; x < 256; ++x)
        if (rb[x] > B || (rb[x] == B && ri[x] < I)) { B = rb[x]; I = ri[x]; }
      g_idx[tok] = I;
    }
    __syncthreads();
  }
}

// Kernel F: gather, out0 = z + (q - z) fp32, idx fp32, accumulate sum((q-z)^2)
__global__ __launch_bounds__(256) void k_out(const float* __restrict__ z,
                                             float* __restrict__ out0,
                                             float* __restrict__ out2) {
  int tid = threadIdx.x;
  int w = tid >> 6, j = tid & 63;
  int base = blockIdx.x * 64;
  float lsum = 0.f;
  for (int r = 0; r < 16; ++r) {
    int tok = base + w * 16 + r;
    int idx = g_idx[tok];
    float q = g_qcb[(size_t)idx * 64 + j];
    float zv = z[(size_t)tok * 64 + j];
    float d = q - zv;
    out0[(size_t)tok * 64 + j] = zv + d;  // z + (q - z), ref op order
    lsum = fmaf(d, d, lsum);
    if (j == 0) out2[tok] = (float)idx;
  }
  float tot = wave_sum64(lsum);
  if (j == 0) atomicAdd(&g_loss, tot);
}

__global__ void k_loss(float* __restrict__ out1) {
  // commitment_loss == codebook_loss numerically; vq = (1 + 0.25) * mean
  out1[0] = 1.25f * g_loss / 1048576.0f;
}

extern "C" void kernel_launch(void* const* d_in, const int* in_sizes, int n_in,
                              void* d_out, int out_size, void* d_ws, size_t ws_size,
                              hipStream_t stream) {
  const float* z = (const float*)d_in[0];
  const float* cb = (const float*)d_in[1];
  const float* pw = (const float*)d_in[2];
  const float* pb = (const float*)d_in[3];
  // d_in[4] (scale) unused: argmin invariant to positive scale

  float* out0 = (float*)d_out;
  float* out1 = out0 + (size_t)NTOK * DIM;
  float* out2 = out1 + 1;

  hipLaunchKernelGGL(k_codebook, dim3(256), dim3(256), 0, stream, cb, pw, pb);
  hipLaunchKernelGGL(k_znorm, dim3(256), dim3(256), 0, stream, z);
  hipLaunchKernelGGL(k_argmax, dim3(1024), dim3(256), 0, stream);
  hipLaunchKernelGGL(k_combine, dim3(64), dim3(256), 0, stream);
  hipLaunchKernelGGL(k_recheck, dim3(32), dim3(256), 0, stream, z);
  hipLaunchKernelGGL(k_out, dim3(256), dim3(256), 0, stream, z, out0, out2);
  hipLaunchKernelGGL(k_loss, dim3(1), dim3(1), 0, stream, out1);
}

// Round 5
// 654.711 us; speedup vs baseline: 2.2368x; 2.2368x over previous
//
#include <hip/hip_runtime.h>
#include <hip/hip_bf16.h>

// SimVQ: z[16,1024,64] f32, codebook[16384,64] f32, proj_w[64,64] f32, proj_b[64] f32, scale f32
// Outputs (fp32, concat): quantized_st[1048576], vq_loss[1], idx[16384]
// Architecture (r5): bf16-MFMA approximate GEMM (error <= ~4e-3) computes all 16k x 16k scores
// twice: pass1 = per-token max value; pass2 = collect candidates within 8e-3 of max (true
// argmax provably among them). fp64 exact scoring of <=8 candidates/token; full-scan fallback
// for overflow. Scratch in __device__ globals (ws_size proved unreliable in r1/r2).

#define NCODES 16384
#define NTOK   16384
#define DIM    64
#define SPLITS 8
#define MARGIN_MFMA 8e-3f

typedef __attribute__((ext_vector_type(8))) short bf16x8;
typedef __attribute__((ext_vector_type(4))) float f32x4;

__device__ float  g_qcb[NCODES * DIM];   // 4 MB projected codebook fp32 (gather source)
__device__ double g_cn64[NCODES * DIM];  // 8 MB l2norm(qcb) fp64 (exact path)
__device__ short  g_cnb[NCODES * DIM];   // 2 MB l2norm(qcb) bf16 row-major (MFMA B)
__device__ short  g_znb[NTOK * DIM];     // 2 MB l2norm(z)  bf16 row-major (MFMA A)
__device__ unsigned g_topu[NTOK];        // orderable-encoded mfma top-1 value
__device__ int    g_candcnt[NTOK];
__device__ int    g_cand[NTOK * 8];
__device__ int    g_idx[NTOK];
__device__ float  g_loss;

__device__ __forceinline__ float wave_sum64(float v) {
#pragma unroll
  for (int o = 32; o > 0; o >>= 1) v += __shfl_xor(v, o, 64);
  return v;
}
__device__ __forceinline__ double wave_sum64d(double v) {
#pragma unroll
  for (int o = 32; o > 0; o >>= 1) v += __shfl_xor(v, o, 64);
  return v;
}
__device__ __forceinline__ short f2bf(float f) {
  __hip_bfloat16 h = __float2bfloat16(f);
  return *reinterpret_cast<short*>(&h);
}

// A: qcb = cb @ W^T + b in fp64; emit fp32 qcb, fp64 cn64, bf16 cnb (all row-major)
__global__ __launch_bounds__(256) void k_codebook(const float* __restrict__ cb,
                                                  const float* __restrict__ pw,
                                                  const float* __restrict__ pb) {
  __shared__ float Wt[64 * 65];  // Wt[k][j] = W[j][k]
  int tid = threadIdx.x;
  int base = blockIdx.x * 64;
  for (int e = tid; e < 4096; e += 256) {
    int j = e >> 6, k = e & 63;
    Wt[k * 65 + j] = pw[e];
  }
  __syncthreads();
  int w = tid >> 6, j = tid & 63;
  double bj = (double)pb[j];
  for (int r = 0; r < 16; ++r) {
    int n = base + w * 16 + r;
    float cbv = cb[(size_t)n * 64 + j];
    double acc = bj;
#pragma unroll
    for (int k = 0; k < 64; ++k)
      acc = fma((double)__shfl(cbv, k, 64), (double)Wt[k * 65 + j], acc);
    g_qcb[(size_t)n * 64 + j] = (float)acc;
    double tot = wave_sum64d(acc * acc);
    double cn = acc / fmax(sqrt(tot), 1e-12);
    g_cn64[(size_t)n * 64 + j] = cn;
    g_cnb[(size_t)n * 64 + j] = f2bf((float)cn);
  }
}

// B: znb = bf16(l2norm(z rows)); zero per-call state
__global__ __launch_bounds__(256) void k_znorm(const float* __restrict__ z) {
  int tid = threadIdx.x;
  int gid = blockIdx.x * 256 + tid;
  if (gid < NTOK) { g_topu[gid] = 0u; g_candcnt[gid] = 0; }  // 0 == encoded -inf sentinel
  if (gid == 0) g_loss = 0.f;
  int w = tid >> 6, j = tid & 63;
  int base = blockIdx.x * 64;
  for (int r = 0; r < 16; ++r) {
    int row = base + w * 16 + r;
    float v = z[(size_t)row * 64 + j];
    float tot = wave_sum64(v * v);
    g_znb[(size_t)row * 64 + j] = f2bf(v / fmaxf(sqrtf(tot), 1e-12f));
  }
}

// Pass 1: MFMA GEMM, per-token top-1 VALUE across this block's code split.
// Layouts (HW-verified, guide §3): A m=lane&15,k=quad*8+j ; B n=lane&15,k=quad*8+j ;
// C/D col(n)=lane&15, row(m)=quad*4+reg.
__global__ __launch_bounds__(256) void k_mfma1() {
  int tid = threadIdx.x;
  int wave = tid >> 6, lane = tid & 63;
  int quad = lane >> 4, col = lane & 15;
  int tokBlock = blockIdx.x >> 3, split = blockIdx.x & 7;
  int tokBase = tokBlock * 64 + wave * 16;
  const short* za = g_znb + (size_t)(tokBase + col) * 64 + quad * 8;
  bf16x8 a0 = *(const bf16x8*)(za);
  bf16x8 a1 = *(const bf16x8*)(za + 32);
  const short* bp = g_cnb + (size_t)(split * 2048 + col) * 64 + quad * 8;
  bf16x8 b0 = *(const bf16x8*)(bp);
  bf16x8 b1 = *(const bf16x8*)(bp + 32);
  float bv0 = -3.0e38f, bv1 = -3.0e38f, bv2 = -3.0e38f, bv3 = -3.0e38f;
  for (int t = 0; t < 128; ++t) {
    bf16x8 c0 = b0, c1 = b1;
    if (t < 127) {
      const short* np = bp + (size_t)(t + 1) * 1024;  // 16 codes * 64 shorts
      b0 = *(const bf16x8*)(np);
      b1 = *(const bf16x8*)(np + 32);
    }
    f32x4 acc = {0.f, 0.f, 0.f, 0.f};
    acc = __builtin_amdgcn_mfma_f32_16x16x32_bf16(a0, c0, acc, 0, 0, 0);
    acc = __builtin_amdgcn_mfma_f32_16x16x32_bf16(a1, c1, acc, 0, 0, 0);
    bv0 = fmaxf(bv0, acc[0]);
    bv1 = fmaxf(bv1, acc[1]);
    bv2 = fmaxf(bv2, acc[2]);
    bv3 = fmaxf(bv3, acc[3]);
  }
  float bvr[4] = {bv0, bv1, bv2, bv3};
#pragma unroll
  for (int r = 0; r < 4; ++r) {
    float v = bvr[r];
    v = fmaxf(v, __shfl_xor(v, 1, 64));
    v = fmaxf(v, __shfl_xor(v, 2, 64));
    v = fmaxf(v, __shfl_xor(v, 4, 64));
    v = fmaxf(v, __shfl_xor(v, 8, 64));
    if (col == 0) {
      unsigned b = __float_as_uint(v);
      unsigned e = (b & 0x80000000u) ? ~b : (b | 0x80000000u);  // orderable encode
      atomicMax(&g_topu[tokBase + quad * 4 + r], e);
    }
  }
}

// Pass 2: identical MFMA GEMM (deterministic -> identical scores); append candidates
// with score >= top - MARGIN_MFMA. True exact argmax is provably collected.
__global__ __launch_bounds__(256) void k_mfma2() {
  int tid = threadIdx.x;
  int wave = tid >> 6, lane = tid & 63;
  int quad = lane >> 4, col = lane & 15;
  int tokBlock = blockIdx.x >> 3, split = blockIdx.x & 7;
  int tokBase = tokBlock * 64 + wave * 16;
  const short* za = g_znb + (size_t)(tokBase + col) * 64 + quad * 8;
  bf16x8 a0 = *(const bf16x8*)(za);
  bf16x8 a1 = *(const bf16x8*)(za + 32);
  float th[4];
#pragma unroll
  for (int r = 0; r < 4; ++r) {
    unsigned u = g_topu[tokBase + quad * 4 + r];
    unsigned b = (u & 0x80000000u) ? (u & 0x7FFFFFFFu) : ~u;  // orderable decode
    th[r] = __uint_as_float(b) - MARGIN_MFMA;
  }
  const short* bp = g_cnb + (size_t)(split * 2048 + col) * 64 + quad * 8;
  bf16x8 b0 = *(const bf16x8*)(bp);
  bf16x8 b1 = *(const bf16x8*)(bp + 32);
  for (int t = 0; t < 128; ++t) {
    bf16x8 c0 = b0, c1 = b1;
    if (t < 127) {
      const short* np = bp + (size_t)(t + 1) * 1024;
      b0 = *(const bf16x8*)(np);
      b1 = *(const bf16x8*)(np + 32);
    }
    f32x4 acc = {0.f, 0.f, 0.f, 0.f};
    acc = __builtin_amdgcn_mfma_f32_16x16x32_bf16(a0, c0, acc, 0, 0, 0);
    acc = __builtin_amdgcn_mfma_f32_16x16x32_bf16(a1, c1, acc, 0, 0, 0);
    int code = split * 2048 + t * 16 + col;
#pragma unroll
    for (int r = 0; r < 4; ++r) {
      if (acc[r] >= th[r]) {  // rare (~1.3 per token globally)
        int tok = tokBase + quad * 4 + r;
        int p = atomicAdd(&g_candcnt[tok], 1);
        if (p < 8) g_cand[tok * 8 + p] = code;
      }
    }
  }
}

// Exact fp64 scoring of <=8 candidates per token (cnt==1 fast path dominates).
// Normalization of z skipped: positive scale, argmax-invariant.
__global__ __launch_bounds__(256) void k_exact(const float* __restrict__ z) {
  int tok = blockIdx.x * 256 + threadIdx.x;
  if (tok >= NTOK) return;
  int cnt = g_candcnt[tok];
  if (cnt <= 1) { g_idx[tok] = g_cand[tok * 8]; return; }
  if (cnt > 8) return;  // overflow -> k_fullscan
  double zr[64];
#pragma unroll
  for (int k = 0; k < 64; ++k) zr[k] = (double)z[(size_t)tok * 64 + k];
  double best = -1.0e300;
  int bi = 0x7FFFFFFF;
  for (int c = 0; c < cnt; ++c) {
    int code = g_cand[tok * 8 + c];
    const double* cr = g_cn64 + (size_t)code * 64;
    double d = 0.0;
#pragma unroll
    for (int k = 0; k < 64; ++k) d = fma(zr[k], cr[k], d);
    if (d > best || (d == best && code < bi)) { best = d; bi = code; }
  }
  g_idx[tok] = bi;
}

// Fallback: full fp64 scan for candidate-overflow tokens (expected: none).
__global__ __launch_bounds__(256) void k_fullscan(const float* __restrict__ z) {
  __shared__ double zn[64];
  __shared__ double rb[256];
  __shared__ int ri[256];
  int tid = threadIdx.x;
  for (int tok = blockIdx.x; tok < NTOK; tok += gridDim.x) {
    if (g_candcnt[tok] <= 8) continue;  // block-uniform branch
    if (tid < 64) zn[tid] = (double)z[(size_t)tok * 64 + tid];  // unnormalized: scale-invariant
    __syncthreads();
    double best = -1.0e300;
    int bi = 0x7FFFFFFF;
    for (int c = tid; c < NCODES; c += 256) {
      const double* cr = g_cn64 + (size_t)c * 64;
      double d0 = 0.0, d1 = 0.0;
#pragma unroll
      for (int k = 0; k < 64; k += 2) {
        d0 = fma(zn[k], cr[k], d0);
        d1 = fma(zn[k + 1], cr[k + 1], d1);
      }
      double d = d0 + d1;
      if (d > best || (d == best && c < bi)) { best = d; bi = c; }
    }
    rb[tid] = best;
    ri[tid] = bi;
    __syncthreads();
    if (tid == 0) {
      double B = rb[0];
      int I = ri[0];
      for (int x = 1; x < 256; ++x)
        if (rb[x] > B || (rb[x] == B && ri[x] < I)) { B = rb[x]; I = ri[x]; }
      g_idx[tok] = I;
    }
    __syncthreads();
  }
}

// Gather + straight-through + loss partials
__global__ __launch_bounds__(256) void k_out(const float* __restrict__ z,
                                             float* __restrict__ out0,
                                             float* __restrict__ out2) {
  int tid = threadIdx.x;
  int w = tid >> 6, j = tid & 63;
  int base = blockIdx.x * 64;
  float lsum = 0.f;
  for (int r = 0; r < 16; ++r) {
    int tok = base + w * 16 + r;
    int idx = g_idx[tok];
    float q = g_qcb[(size_t)idx * 64 + j];
    float zv = z[(size_t)tok * 64 + j];
    float d = q - zv;
    out0[(size_t)tok * 64 + j] = zv + d;  // z + (q - z), ref op order
    lsum = fmaf(d, d, lsum);
    if (j == 0) out2[tok] = (float)idx;
  }
  float tot = wave_sum64(lsum);
  if (j == 0) atomicAdd(&g_loss, tot);
}

__global__ void k_loss(float* __restrict__ out1) {
  // commitment_loss == codebook_loss numerically; vq = (1 + 0.25) * mean
  out1[0] = 1.25f * g_loss / 1048576.0f;
}

extern "C" void kernel_launch(void* const* d_in, const int* in_sizes, int n_in,
                              void* d_out, int out_size, void* d_ws, size_t ws_size,
                              hipStream_t stream) {
  const float* z = (const float*)d_in[0];
  const float* cb = (const float*)d_in[1];
  const float* pw = (const float*)d_in[2];
  const float* pb = (const float*)d_in[3];
  // d_in[4] (scale) unused: argmin invariant to positive scale

  float* out0 = (float*)d_out;
  float* out1 = out0 + (size_t)NTOK * DIM;
  float* out2 = out1 + 1;

  hipLaunchKernelGGL(k_codebook, dim3(256), dim3(256), 0, stream, cb, pw, pb);
  hipLaunchKernelGGL(k_znorm, dim3(256), dim3(256), 0, stream, z);
  hipLaunchKernelGGL(k_mfma1, dim3(2048), dim3(256), 0, stream);
  hipLaunchKernelGGL(k_mfma2, dim3(2048), dim3(256), 0, stream);
  hipLaunchKernelGGL(k_exact, dim3(64), dim3(256), 0, stream, z);
  hipLaunchKernelGGL(k_fullscan, dim3(64), dim3(256), 0, stream, z);
  hipLaunchKernelGGL(k_out, dim3(256), dim3(256), 0, stream, z, out0, out2);
  hipLaunchKernelGGL(k_loss, dim3(1), dim3(1), 0, stream, out1);
}

// Round 6
// 272.276 us; speedup vs baseline: 5.3786x; 2.4046x over previous
//
#include <hip/hip_runtime.h>
#include <hip/hip_bf16.h>

// SimVQ: z[16,1024,64] f32, codebook[16384,64] f32, proj_w[64,64] f32, proj_b[64] f32, scale f32
// Outputs (fp32, concat): quantized_st[1048576], vq_loss[1], idx[16384]
// r6: MFMA GEMM restructured — 128 tokens/block (32/wave), B staged via global_load_lds into
// 16KB LDS stages shared by 4 waves (traffic 2GB -> 256MB/pass), XOR-swizzled so B ds_read_b128
// is conflict-free. k_codebook de-shfl'd (LDS-broadcast fp64). Candidate margin logic unchanged
// (proven r5): pass1 top value, pass2 collect within 8e-3, fp64 exact arbiter.

#define NCODES 16384
#define NTOK   16384
#define DIM    64
#define MARGIN_MFMA 8e-3f

typedef __attribute__((ext_vector_type(8))) short bf16x8;
typedef __attribute__((ext_vector_type(4))) float f32x4;
#define GLOBAL_AS __attribute__((address_space(1)))
#define LDS_AS    __attribute__((address_space(3)))

__device__ float  g_qcb[NCODES * DIM];   // 4 MB projected codebook fp32 (gather source)
__device__ double g_cn64[NCODES * DIM];  // 8 MB l2norm(qcb) fp64 (exact path)
__device__ short  g_cnb[NCODES * DIM];   // 2 MB l2norm(qcb) bf16 row-major (MFMA B)
__device__ short  g_znb[NTOK * DIM];     // 2 MB l2norm(z)  bf16 row-major (MFMA A)
__device__ unsigned g_topu[NTOK];        // orderable-encoded mfma top-1 value
__device__ int    g_candcnt[NTOK];
__device__ int    g_cand[NTOK * 8];
__device__ int    g_idx[NTOK];
__device__ float  g_loss;

__device__ __forceinline__ float wave_sum64(float v) {
#pragma unroll
  for (int o = 32; o > 0; o >>= 1) v += __shfl_xor(v, o, 64);
  return v;
}
__device__ __forceinline__ double wave_sum64d(double v) {
#pragma unroll
  for (int o = 32; o > 0; o >>= 1) v += __shfl_xor(v, o, 64);
  return v;
}
__device__ __forceinline__ short f2bf(float f) {
  __hip_bfloat16 h = __float2bfloat16(f);
  return *reinterpret_cast<short*>(&h);
}

// A: qcb = cb @ W^T + b in fp64 via LDS broadcast (no shfl chains); 32 rows/block, 512 blocks.
__global__ __launch_bounds__(256) void k_codebook(const float* __restrict__ cb,
                                                  const float* __restrict__ pw,
                                                  const float* __restrict__ pb) {
  __shared__ float Wt[64 * 65];   // Wt[k][j] = W[j][k], 2-way bank alias (free)
  __shared__ float cbs[32 * 65];  // staged cb rows, read as lane-broadcast
  int tid = threadIdx.x;
  int base = blockIdx.x * 32;
  for (int e = tid; e < 4096; e += 256) {
    int j = e >> 6, k = e & 63;
    Wt[k * 65 + j] = pw[e];
  }
  for (int e = tid; e < 2048; e += 256) {
    int row = e >> 6, k = e & 63;
    cbs[row * 65 + k] = cb[(size_t)(base + row) * 64 + k];
  }
  __syncthreads();
  int w = tid >> 6, j = tid & 63;
  double bj = (double)pb[j];
  for (int rr = 0; rr < 8; ++rr) {
    int nl = w * 8 + rr;
    int n = base + nl;
    double acc = bj;
#pragma unroll
    for (int k = 0; k < 64; ++k)
      acc = fma((double)cbs[nl * 65 + k], (double)Wt[k * 65 + j], acc);
    g_qcb[(size_t)n * 64 + j] = (float)acc;
    double tot = wave_sum64d(acc * acc);
    double cn = acc / fmax(sqrt(tot), 1e-12);
    g_cn64[(size_t)n * 64 + j] = cn;
    g_cnb[(size_t)n * 64 + j] = f2bf((float)cn);
  }
}

// B: znb = bf16(l2norm(z rows)); zero per-call state
__global__ __launch_bounds__(256) void k_znorm(const float* __restrict__ z) {
  int tid = threadIdx.x;
  int gid = blockIdx.x * 256 + tid;
  if (gid < NTOK) { g_topu[gid] = 0u; g_candcnt[gid] = 0; }
  if (gid == 0) g_loss = 0.f;
  int w = tid >> 6, j = tid & 63;
  int base = blockIdx.x * 64;
  for (int r = 0; r < 16; ++r) {
    int row = base + w * 16 + r;
    float v = z[(size_t)row * 64 + j];
    float tot = wave_sum64(v * v);
    g_znb[(size_t)row * 64 + j] = f2bf(v / fmaxf(sqrtf(tot), 1e-12f));
  }
}

// Shared GEMM core: grid = 128 token-blocks x 8 splits = 1024 blocks, 4 waves/block.
// Wave owns 32 tokens (2 A-frags). B staged 128 codes (16KB) per barrier via global_load_lds
// (width 16), XOR-swizzled: LDS[row][s] = G[row][s ^ (row&7)] so frag ds_read_b128 hits
// 8 distinct 4-bank groups x2 lanes (2-way = free, m136).
// MFMA layouts (HW-proven r5): A m=col,k=quad*8+j ; B n=col,k=quad*8+j ; C/D m=quad*4+reg,n=col.

__global__ __launch_bounds__(256) void k_mfma1() {
  __shared__ short smB[8192];  // 16 KB: 128 codes x 64 shorts
  int tid = threadIdx.x;
  int wave = tid >> 6, lane = tid & 63;
  int quad = lane >> 4, col = lane & 15;
  int tokBlock = blockIdx.x >> 3, split = blockIdx.x & 7;
  int tokBase = tokBlock * 128 + wave * 32;

  const short* za = g_znb + (size_t)(tokBase + col) * 64 + quad * 8;
  bf16x8 a00 = *(const bf16x8*)(za);
  bf16x8 a01 = *(const bf16x8*)(za + 32);
  bf16x8 a10 = *(const bf16x8*)(za + 16 * 64);
  bf16x8 a11 = *(const bf16x8*)(za + 16 * 64 + 32);

  float m0[4], m1[4];
#pragma unroll
  for (int r = 0; r < 4; ++r) { m0[r] = -3.0e38f; m1[r] = -3.0e38f; }

  const char* gsplit = (const char*)(g_cnb + (size_t)split * 2048 * 64);
  int x = col & 7;
  int s0off = ((quad ^ x) << 3);
  int s1off = (((4 | quad) ^ x) << 3);

  for (int s = 0; s < 16; ++s) {
    const char* gbase = gsplit + (size_t)s * 16384;
#pragma unroll
    for (int i = 0; i < 4; ++i) {
      int cidx = wave * 256 + i * 64 + lane;
      int row = cidx >> 3, sw = cidx & 7;
      int gch = sw ^ (row & 7);
      __builtin_amdgcn_global_load_lds(
          (const GLOBAL_AS void*)(gbase + row * 128 + gch * 16),
          (LDS_AS void*)(smB + wave * 2048 + i * 512), 16, 0, 0);
    }
    __syncthreads();
#pragma unroll
    for (int t = 0; t < 8; ++t) {
      const short* lb = smB + (t * 16 + col) * 64;
      bf16x8 b0 = *(const bf16x8*)(lb + s0off);
      bf16x8 b1 = *(const bf16x8*)(lb + s1off);
      f32x4 acc = {0.f, 0.f, 0.f, 0.f};
      acc = __builtin_amdgcn_mfma_f32_16x16x32_bf16(a00, b0, acc, 0, 0, 0);
      acc = __builtin_amdgcn_mfma_f32_16x16x32_bf16(a01, b1, acc, 0, 0, 0);
      f32x4 acd = {0.f, 0.f, 0.f, 0.f};
      acd = __builtin_amdgcn_mfma_f32_16x16x32_bf16(a10, b0, acd, 0, 0, 0);
      acd = __builtin_amdgcn_mfma_f32_16x16x32_bf16(a11, b1, acd, 0, 0, 0);
#pragma unroll
      for (int r = 0; r < 4; ++r) {
        m0[r] = fmaxf(m0[r], acc[r]);
        m1[r] = fmaxf(m1[r], acd[r]);
      }
    }
    __syncthreads();
  }
#pragma unroll
  for (int f = 0; f < 2; ++f) {
#pragma unroll
    for (int r = 0; r < 4; ++r) {
      float v = f ? m1[r] : m0[r];
      v = fmaxf(v, __shfl_xor(v, 1, 64));
      v = fmaxf(v, __shfl_xor(v, 2, 64));
      v = fmaxf(v, __shfl_xor(v, 4, 64));
      v = fmaxf(v, __shfl_xor(v, 8, 64));
      if (col == 0) {
        unsigned b = __float_as_uint(v);
        unsigned e = (b & 0x80000000u) ? ~b : (b | 0x80000000u);
        atomicMax(&g_topu[tokBase + f * 16 + quad * 4 + r], e);
      }
    }
  }
}

__global__ __launch_bounds__(256) void k_mfma2() {
  __shared__ short smB[8192];
  int tid = threadIdx.x;
  int wave = tid >> 6, lane = tid & 63;
  int quad = lane >> 4, col = lane & 15;
  int tokBlock = blockIdx.x >> 3, split = blockIdx.x & 7;
  int tokBase = tokBlock * 128 + wave * 32;

  const short* za = g_znb + (size_t)(tokBase + col) * 64 + quad * 8;
  bf16x8 a00 = *(const bf16x8*)(za);
  bf16x8 a01 = *(const bf16x8*)(za + 32);
  bf16x8 a10 = *(const bf16x8*)(za + 16 * 64);
  bf16x8 a11 = *(const bf16x8*)(za + 16 * 64 + 32);

  float th0[4], th1[4];
#pragma unroll
  for (int r = 0; r < 4; ++r) {
    unsigned u0 = g_topu[tokBase + quad * 4 + r];
    unsigned b0_ = (u0 & 0x80000000u) ? (u0 & 0x7FFFFFFFu) : ~u0;
    th0[r] = __uint_as_float(b0_) - MARGIN_MFMA;
    unsigned u1 = g_topu[tokBase + 16 + quad * 4 + r];
    unsigned b1_ = (u1 & 0x80000000u) ? (u1 & 0x7FFFFFFFu) : ~u1;
    th1[r] = __uint_as_float(b1_) - MARGIN_MFMA;
  }

  const char* gsplit = (const char*)(g_cnb + (size_t)split * 2048 * 64);
  int x = col & 7;
  int s0off = ((quad ^ x) << 3);
  int s1off = (((4 | quad) ^ x) << 3);

  for (int s = 0; s < 16; ++s) {
    const char* gbase = gsplit + (size_t)s * 16384;
#pragma unroll
    for (int i = 0; i < 4; ++i) {
      int cidx = wave * 256 + i * 64 + lane;
      int row = cidx >> 3, sw = cidx & 7;
      int gch = sw ^ (row & 7);
      __builtin_amdgcn_global_load_lds(
          (const GLOBAL_AS void*)(gbase + row * 128 + gch * 16),
          (LDS_AS void*)(smB + wave * 2048 + i * 512), 16, 0, 0);
    }
    __syncthreads();
#pragma unroll
    for (int t = 0; t < 8; ++t) {
      const short* lb = smB + (t * 16 + col) * 64;
      bf16x8 b0 = *(const bf16x8*)(lb + s0off);
      bf16x8 b1 = *(const bf16x8*)(lb + s1off);
      f32x4 acc = {0.f, 0.f, 0.f, 0.f};
      acc = __builtin_amdgcn_mfma_f32_16x16x32_bf16(a00, b0, acc, 0, 0, 0);
      acc = __builtin_amdgcn_mfma_f32_16x16x32_bf16(a01, b1, acc, 0, 0, 0);
      f32x4 acd = {0.f, 0.f, 0.f, 0.f};
      acd = __builtin_amdgcn_mfma_f32_16x16x32_bf16(a10, b0, acd, 0, 0, 0);
      acd = __builtin_amdgcn_mfma_f32_16x16x32_bf16(a11, b1, acd, 0, 0, 0);
      int code = split * 2048 + s * 128 + t * 16 + col;
#pragma unroll
      for (int r = 0; r < 4; ++r) {
        if (acc[r] >= th0[r]) {
          int tok = tokBase + quad * 4 + r;
          int p = atomicAdd(&g_candcnt[tok], 1);
          if (p < 8) g_cand[tok * 8 + p] = code;
        }
        if (acd[r] >= th1[r]) {
          int tok = tokBase + 16 + quad * 4 + r;
          int p = atomicAdd(&g_candcnt[tok], 1);
          if (p < 8) g_cand[tok * 8 + p] = code;
        }
      }
    }
    __syncthreads();
  }
}

// Exact fp64 scoring of <=8 candidates per token (cnt==1 fast path dominates).
__global__ __launch_bounds__(256) void k_exact(const float* __restrict__ z) {
  int tok = blockIdx.x * 256 + threadIdx.x;
  if (tok >= NTOK) return;
  int cnt = g_candcnt[tok];
  if (cnt <= 1) { g_idx[tok] = g_cand[tok * 8]; return; }
  if (cnt > 8) return;  // overflow -> k_fullscan
  double zr[64];
#pragma unroll
  for (int k = 0; k < 64; ++k) zr[k] = (double)z[(size_t)tok * 64 + k];
  double best = -1.0e300;
  int bi = 0x7FFFFFFF;
  for (int c = 0; c < cnt; ++c) {
    int code = g_cand[tok * 8 + c];
    const double* cr = g_cn64 + (size_t)code * 64;
    double d = 0.0;
#pragma unroll
    for (int k = 0; k < 64; ++k) d = fma(zr[k], cr[k], d);
    if (d > best || (d == best && code < bi)) { best = d; bi = code; }
  }
  g_idx[tok] = bi;
}

// Fallback: full fp64 scan for candidate-overflow tokens (expected: none).
__global__ __launch_bounds__(256) void k_fullscan(const float* __restrict__ z) {
  __shared__ double zn[64];
  __shared__ double rb[256];
  __shared__ int ri[256];
  int tid = threadIdx.x;
  for (int tok = blockIdx.x; tok < NTOK; tok += gridDim.x) {
    if (g_candcnt[tok] <= 8) continue;  // block-uniform branch
    if (tid < 64) zn[tid] = (double)z[(size_t)tok * 64 + tid];
    __syncthreads();
    double best = -1.0e300;
    int bi = 0x7FFFFFFF;
    for (int c = tid; c < NCODES; c += 256) {
      const double* cr = g_cn64 + (size_t)c * 64;
      double d0 = 0.0, d1 = 0.0;
#pragma unroll
      for (int k = 0; k < 64; k += 2) {
        d0 = fma(zn[k], cr[k], d0);
        d1 = fma(zn[k + 1], cr[k + 1], d1);
      }
      double d = d0 + d1;
      if (d > best || (d == best && c < bi)) { best = d; bi = c; }
    }
    rb[tid] = best;
    ri[tid] = bi;
    __syncthreads();
    if (tid == 0) {
      double B = rb[0];
      int I = ri[0];
      for (int xx = 1; xx < 256; ++xx)
        if (rb[xx] > B || (rb[xx] == B && ri[xx] < I)) { B = rb[xx]; I = ri[xx]; }
      g_idx[tok] = I;
    }
    __syncthreads();
  }
}

// Gather + straight-through + loss partials
__global__ __launch_bounds__(256) void k_out(const float* __restrict__ z,
                                             float* __restrict__ out0,
                                             float* __restrict__ out2) {
  int tid = threadIdx.x;
  int w = tid >> 6, j = tid & 63;
  int base = blockIdx.x * 64;
  float lsum = 0.f;
  for (int r = 0; r < 16; ++r) {
    int tok = base + w * 16 + r;
    int idx = g_idx[tok];
    float q = g_qcb[(size_t)idx * 64 + j];
    float zv = z[(size_t)tok * 64 + j];
    float d = q - zv;
    out0[(size_t)tok * 64 + j] = zv + d;  // z + (q - z), ref op order
    lsum = fmaf(d, d, lsum);
    if (j == 0) out2[tok] = (float)idx;
  }
  float tot = wave_sum64(lsum);
  if (j == 0) atomicAdd(&g_loss, tot);
}

__global__ void k_loss(float* __restrict__ out1) {
  out1[0] = 1.25f * g_loss / 1048576.0f;  // commitment == codebook numerically
}

extern "C" void kernel_launch(void* const* d_in, const int* in_sizes, int n_in,
                              void* d_out, int out_size, void* d_ws, size_t ws_size,
                              hipStream_t stream) {
  const float* z = (const float*)d_in[0];
  const float* cb = (const float*)d_in[1];
  const float* pw = (const float*)d_in[2];
  const float* pb = (const float*)d_in[3];
  // d_in[4] (scale) unused: argmin invariant to positive scale

  float* out0 = (float*)d_out;
  float* out1 = out0 + (size_t)NTOK * DIM;
  float* out2 = out1 + 1;

  hipLaunchKernelGGL(k_codebook, dim3(512), dim3(256), 0, stream, cb, pw, pb);
  hipLaunchKernelGGL(k_znorm, dim3(256), dim3(256), 0, stream, z);
  hipLaunchKernelGGL(k_mfma1, dim3(1024), dim3(256), 0, stream);
  hipLaunchKernelGGL(k_mfma2, dim3(1024), dim3(256), 0, stream);
  hipLaunchKernelGGL(k_exact, dim3(64), dim3(256), 0, stream, z);
  hipLaunchKernelGGL(k_fullscan, dim3(64), dim3(256), 0, stream, z);
  hipLaunchKernelGGL(k_out, dim3(256), dim3(256), 0, stream, z, out0, out2);
  hipLaunchKernelGGL(k_loss, dim3(1), dim3(1), 0, stream, out1);
}

// Round 7
// 250.822 us; speedup vs baseline: 5.8387x; 1.0855x over previous
//
#include <hip/hip_runtime.h>
#include <hip/hip_bf16.h>

// SimVQ: z[16,1024,64] f32, codebook[16384,64] f32, proj_w[64,64] f32, proj_b[64] f32, scale f32
// Outputs (fp32, concat): quantized_st[1048576], vq_loss[1], idx[16384]
// r7: (a) overflow-list replaces k_fullscan's 61µs idle token scan; (b) MFMA passes: 256
// tokens/block (64/wave, 4 A-frags), double-buffered LDS B-staging with ONE barrier/stage
// (prefetch s+1 before computing s -> vmcnt drain hidden). Margin scheme unchanged (proven
// r5/r6): pass1 top value, pass2 collect within 8e-3 (bf16 dot err <= 4e-3), fp64 arbiter.

#define NCODES 16384
#define NTOK   16384
#define DIM    64
#define MARGIN_MFMA 8e-3f

typedef __attribute__((ext_vector_type(8))) short bf16x8;
typedef __attribute__((ext_vector_type(4))) float f32x4;
#define GLOBAL_AS __attribute__((address_space(1)))
#define LDS_AS    __attribute__((address_space(3)))

__device__ float  g_qcb[NCODES * DIM];   // 4 MB projected codebook fp32 (gather source)
__device__ double g_cn64[NCODES * DIM];  // 8 MB l2norm(qcb) fp64 (exact path)
__device__ short  g_cnb[NCODES * DIM];   // 2 MB l2norm(qcb) bf16 row-major (MFMA B)
__device__ short  g_znb[NTOK * DIM];     // 2 MB l2norm(z)  bf16 row-major (MFMA A)
__device__ unsigned g_topu[NTOK];        // orderable-encoded mfma top-1 value
__device__ int    g_candcnt[NTOK];
__device__ int    g_cand[NTOK * 8];
__device__ int    g_idx[NTOK];
__device__ int    g_ovcnt;               // overflow-token count (expected 0)
__device__ int    g_ovlist[NTOK];
__device__ float  g_loss;

__device__ __forceinline__ float wave_sum64(float v) {
#pragma unroll
  for (int o = 32; o > 0; o >>= 1) v += __shfl_xor(v, o, 64);
  return v;
}
__device__ __forceinline__ double wave_sum64d(double v) {
#pragma unroll
  for (int o = 32; o > 0; o >>= 1) v += __shfl_xor(v, o, 64);
  return v;
}
__device__ __forceinline__ short f2bf(float f) {
  __hip_bfloat16 h = __float2bfloat16(f);
  return *reinterpret_cast<short*>(&h);
}

// A: qcb = cb @ W^T + b in fp64 via LDS broadcast; 32 rows/block, 512 blocks.
__global__ __launch_bounds__(256) void k_codebook(const float* __restrict__ cb,
                                                  const float* __restrict__ pw,
                                                  const float* __restrict__ pb) {
  __shared__ float Wt[64 * 65];   // Wt[k][j] = W[j][k]
  __shared__ float cbs[32 * 65];  // staged cb rows
  int tid = threadIdx.x;
  int base = blockIdx.x * 32;
  for (int e = tid; e < 4096; e += 256) {
    int j = e >> 6, k = e & 63;
    Wt[k * 65 + j] = pw[e];
  }
  for (int e = tid; e < 2048; e += 256) {
    int row = e >> 6, k = e & 63;
    cbs[row * 65 + k] = cb[(size_t)(base + row) * 64 + k];
  }
  __syncthreads();
  int w = tid >> 6, j = tid & 63;
  double bj = (double)pb[j];
  for (int rr = 0; rr < 8; ++rr) {
    int nl = w * 8 + rr;
    int n = base + nl;
    double acc = bj;
#pragma unroll
    for (int k = 0; k < 64; ++k)
      acc = fma((double)cbs[nl * 65 + k], (double)Wt[k * 65 + j], acc);
    g_qcb[(size_t)n * 64 + j] = (float)acc;
    double tot = wave_sum64d(acc * acc);
    double cn = acc / fmax(sqrt(tot), 1e-12);
    g_cn64[(size_t)n * 64 + j] = cn;
    g_cnb[(size_t)n * 64 + j] = f2bf((float)cn);
  }
}

// B: znb = bf16(l2norm(z rows)); zero per-call state
__global__ __launch_bounds__(256) void k_znorm(const float* __restrict__ z) {
  int tid = threadIdx.x;
  int gid = blockIdx.x * 256 + tid;
  if (gid < NTOK) { g_topu[gid] = 0u; g_candcnt[gid] = 0; }
  if (gid == 0) { g_loss = 0.f; g_ovcnt = 0; }
  int w = tid >> 6, j = tid & 63;
  int base = blockIdx.x * 64;
  for (int r = 0; r < 16; ++r) {
    int row = base + w * 16 + r;
    float v = z[(size_t)row * 64 + j];
    float tot = wave_sum64(v * v);
    g_znb[(size_t)row * 64 + j] = f2bf(v / fmaxf(sqrtf(tot), 1e-12f));
  }
}

// GEMM core: grid = 64 token-blocks x 8 splits = 512 blocks (2/CU), 4 waves/block.
// Wave owns 64 tokens (4 A-frag pairs). B double-buffered: 128 codes (16KB) per stage via
// global_load_lds width-16, XOR-swizzled (LDS[row][c] = G[row][c ^ (row&7)]) so B-frag
// ds_read_b128 is 2-way bank-aliased (free, m136). ONE barrier per stage: prefetch s+1
// into buf^1 before computing s from buf (vmcnt drain overlapped with compute).
// MFMA layouts (HW-proven): A m=col,k=quad*8+j ; B n=col,k=quad*8+j ; C/D m=quad*4+reg,n=col.

__global__ __launch_bounds__(256) void k_mfma1() {
  __shared__ __align__(16) short smB[2][8192];  // 2 x 16 KB: 128 codes x 64 shorts
  int tid = threadIdx.x;
  int wave = tid >> 6, lane = tid & 63;
  int quad = lane >> 4, col = lane & 15;
  int tokBlock = blockIdx.x >> 3, split = blockIdx.x & 7;
  int tokBase = tokBlock * 256 + wave * 64;

  const short* za = g_znb + (size_t)(tokBase + col) * 64 + quad * 8;
  bf16x8 A0[4], A1[4];
#pragma unroll
  for (int f = 0; f < 4; ++f) {
    A0[f] = *(const bf16x8*)(za + f * 16 * 64);
    A1[f] = *(const bf16x8*)(za + f * 16 * 64 + 32);
  }
  float m[4][4];
#pragma unroll
  for (int f = 0; f < 4; ++f)
#pragma unroll
    for (int r = 0; r < 4; ++r) m[f][r] = -3.0e38f;

  const char* gsplit = (const char*)(g_cnb + (size_t)split * 2048 * 64);
  int x = col & 7;
  int s0off = ((quad ^ x) << 3);
  int s1off = (((4 | quad) ^ x) << 3);

  int goff[4];
#pragma unroll
  for (int i = 0; i < 4; ++i) {
    int cidx = wave * 256 + i * 64 + lane;
    int row = cidx >> 3, sw = cidx & 7;
    goff[i] = row * 128 + (sw ^ (row & 7)) * 16;
  }

#pragma unroll
  for (int i = 0; i < 4; ++i)
    __builtin_amdgcn_global_load_lds((const GLOBAL_AS void*)(gsplit + goff[i]),
                                     (LDS_AS void*)(&smB[0][wave * 2048 + i * 512]), 16, 0, 0);
  __syncthreads();

  int p = 0;
  for (int s = 0; s < 16; ++s) {
    if (s < 15) {
      const char* gb = gsplit + (size_t)(s + 1) * 16384;
#pragma unroll
      for (int i = 0; i < 4; ++i)
        __builtin_amdgcn_global_load_lds((const GLOBAL_AS void*)(gb + goff[i]),
                                         (LDS_AS void*)(&smB[p ^ 1][wave * 2048 + i * 512]),
                                         16, 0, 0);
    }
    const short* bufp = smB[p];
#pragma unroll
    for (int t = 0; t < 8; ++t) {
      const short* lb = bufp + (t * 16 + col) * 64;
      bf16x8 b0 = *(const bf16x8*)(lb + s0off);
      bf16x8 b1 = *(const bf16x8*)(lb + s1off);
#pragma unroll
      for (int f = 0; f < 4; ++f) {
        f32x4 acc = {0.f, 0.f, 0.f, 0.f};
        acc = __builtin_amdgcn_mfma_f32_16x16x32_bf16(A0[f], b0, acc, 0, 0, 0);
        acc = __builtin_amdgcn_mfma_f32_16x16x32_bf16(A1[f], b1, acc, 0, 0, 0);
#pragma unroll
        for (int r = 0; r < 4; ++r) m[f][r] = fmaxf(m[f][r], acc[r]);
      }
    }
    __syncthreads();  // publishes buf p^1 (loads drained), protects buf p for next prefetch
    p ^= 1;
  }

#pragma unroll
  for (int f = 0; f < 4; ++f)
#pragma unroll
    for (int r = 0; r < 4; ++r) {
      float v = m[f][r];
      v = fmaxf(v, __shfl_xor(v, 1, 64));
      v = fmaxf(v, __shfl_xor(v, 2, 64));
      v = fmaxf(v, __shfl_xor(v, 4, 64));
      v = fmaxf(v, __shfl_xor(v, 8, 64));
      if (col == 0) {
        unsigned b = __float_as_uint(v);
        unsigned e = (b & 0x80000000u) ? ~b : (b | 0x80000000u);
        atomicMax(&g_topu[tokBase + f * 16 + quad * 4 + r], e);
      }
    }
}

__global__ __launch_bounds__(256) void k_mfma2() {
  __shared__ __align__(16) short smB[2][8192];
  int tid = threadIdx.x;
  int wave = tid >> 6, lane = tid & 63;
  int quad = lane >> 4, col = lane & 15;
  int tokBlock = blockIdx.x >> 3, split = blockIdx.x & 7;
  int tokBase = tokBlock * 256 + wave * 64;

  const short* za = g_znb + (size_t)(tokBase + col) * 64 + quad * 8;
  bf16x8 A0[4], A1[4];
#pragma unroll
  for (int f = 0; f < 4; ++f) {
    A0[f] = *(const bf16x8*)(za + f * 16 * 64);
    A1[f] = *(const bf16x8*)(za + f * 16 * 64 + 32);
  }
  float th[4][4];
#pragma unroll
  for (int f = 0; f < 4; ++f)
#pragma unroll
    for (int r = 0; r < 4; ++r) {
      unsigned u = g_topu[tokBase + f * 16 + quad * 4 + r];
      unsigned b = (u & 0x80000000u) ? (u & 0x7FFFFFFFu) : ~u;
      th[f][r] = __uint_as_float(b) - MARGIN_MFMA;
    }

  const char* gsplit = (const char*)(g_cnb + (size_t)split * 2048 * 64);
  int x = col & 7;
  int s0off = ((quad ^ x) << 3);
  int s1off = (((4 | quad) ^ x) << 3);

  int goff[4];
#pragma unroll
  for (int i = 0; i < 4; ++i) {
    int cidx = wave * 256 + i * 64 + lane;
    int row = cidx >> 3, sw = cidx & 7;
    goff[i] = row * 128 + (sw ^ (row & 7)) * 16;
  }

#pragma unroll
  for (int i = 0; i < 4; ++i)
    __builtin_amdgcn_global_load_lds((const GLOBAL_AS void*)(gsplit + goff[i]),
                                     (LDS_AS void*)(&smB[0][wave * 2048 + i * 512]), 16, 0, 0);
  __syncthreads();

  int codeB = split * 2048 + col;
  int p = 0;
  for (int s = 0; s < 16; ++s) {
    if (s < 15) {
      const char* gb = gsplit + (size_t)(s + 1) * 16384;
#pragma unroll
      for (int i = 0; i < 4; ++i)
        __builtin_amdgcn_global_load_lds((const GLOBAL_AS void*)(gb + goff[i]),
                                         (LDS_AS void*)(&smB[p ^ 1][wave * 2048 + i * 512]),
                                         16, 0, 0);
    }
    const short* bufp = smB[p];
#pragma unroll
    for (int t = 0; t < 8; ++t) {
      const short* lb = bufp + (t * 16 + col) * 64;
      bf16x8 b0 = *(const bf16x8*)(lb + s0off);
      bf16x8 b1 = *(const bf16x8*)(lb + s1off);
      int code = codeB + s * 128 + t * 16;
#pragma unroll
      for (int f = 0; f < 4; ++f) {
        f32x4 acc = {0.f, 0.f, 0.f, 0.f};
        acc = __builtin_amdgcn_mfma_f32_16x16x32_bf16(A0[f], b0, acc, 0, 0, 0);
        acc = __builtin_amdgcn_mfma_f32_16x16x32_bf16(A1[f], b1, acc, 0, 0, 0);
#pragma unroll
        for (int r = 0; r < 4; ++r) {
          if (acc[r] >= th[f][r]) {  // rare (~1.3 per token globally)
            int tok = tokBase + f * 16 + quad * 4 + r;
            int pos = atomicAdd(&g_candcnt[tok], 1);
            if (pos < 8) g_cand[tok * 8 + pos] = code;
          }
        }
      }
    }
    __syncthreads();
    p ^= 1;
  }
}

// Exact fp64 scoring of <=8 candidates per token; overflow -> g_ovlist (expected none).
__global__ __launch_bounds__(256) void k_exact(const float* __restrict__ z) {
  int tok = blockIdx.x * 256 + threadIdx.x;
  if (tok >= NTOK) return;
  int cnt = g_candcnt[tok];
  if (cnt <= 1) { g_idx[tok] = g_cand[tok * 8]; return; }
  if (cnt > 8) {
    int p = atomicAdd(&g_ovcnt, 1);
    g_ovlist[p] = tok;
    return;
  }
  double zr[64];
#pragma unroll
  for (int k = 0; k < 64; ++k) zr[k] = (double)z[(size_t)tok * 64 + k];
  double best = -1.0e300;
  int bi = 0x7FFFFFFF;
  for (int c = 0; c < cnt; ++c) {
    int code = g_cand[tok * 8 + c];
    const double* cr = g_cn64 + (size_t)code * 64;
    double d = 0.0;
#pragma unroll
    for (int k = 0; k < 64; ++k) d = fma(zr[k], cr[k], d);
    if (d > best || (d == best && code < bi)) { best = d; bi = code; }
  }
  g_idx[tok] = bi;
}

// Fallback: full fp64 scan, only over the overflow list (normally empty -> ~2us).
__global__ __launch_bounds__(256) void k_fullscan(const float* __restrict__ z) {
  __shared__ double zn[64];
  __shared__ double rb[256];
  __shared__ int ri[256];
  int tid = threadIdx.x;
  int nov = g_ovcnt;
  for (int f = blockIdx.x; f < nov; f += gridDim.x) {
    int tok = g_ovlist[f];
    if (tid < 64) zn[tid] = (double)z[(size_t)tok * 64 + tid];  // unnormalized: scale-invariant
    __syncthreads();
    double best = -1.0e300;
    int bi = 0x7FFFFFFF;
    for (int c = tid; c < NCODES; c += 256) {
      const double* cr = g_cn64 + (size_t)c * 64;
      double d0 = 0.0, d1 = 0.0;
#pragma unroll
      for (int k = 0; k < 64; k += 2) {
        d0 = fma(zn[k], cr[k], d0);
        d1 = fma(zn[k + 1], cr[k + 1], d1);
      }
      double d = d0 + d1;
      if (d > best || (d == best && c < bi)) { best = d; bi = c; }
    }
    rb[tid] = best;
    ri[tid] = bi;
    __syncthreads();
    if (tid == 0) {
      double B = rb[0];
      int I = ri[0];
      for (int xx = 1; xx < 256; ++xx)
        if (rb[xx] > B || (rb[xx] == B && ri[xx] < I)) { B = rb[xx]; I = ri[xx]; }
      g_idx[tok] = I;
    }
    __syncthreads();
  }
}

// Gather + straight-through + loss partials
__global__ __launch_bounds__(256) void k_out(const float* __restrict__ z,
                                             float* __restrict__ out0,
                                             float* __restrict__ out2) {
  int tid = threadIdx.x;
  int w = tid >> 6, j = tid & 63;
  int base = blockIdx.x * 64;
  float lsum = 0.f;
  for (int r = 0; r < 16; ++r) {
    int tok = base + w * 16 + r;
    int idx = g_idx[tok];
    float q = g_qcb[(size_t)idx * 64 + j];
    float zv = z[(size_t)tok * 64 + j];
    float d = q - zv;
    out0[(size_t)tok * 64 + j] = zv + d;  // z + (q - z), ref op order
    lsum = fmaf(d, d, lsum);
    if (j == 0) out2[tok] = (float)idx;
  }
  float tot = wave_sum64(lsum);
  if (j == 0) atomicAdd(&g_loss, tot);
}

__global__ void k_loss(float* __restrict__ out1) {
  out1[0] = 1.25f * g_loss / 1048576.0f;  // commitment == codebook numerically
}

extern "C" void kernel_launch(void* const* d_in, const int* in_sizes, int n_in,
                              void* d_out, int out_size, void* d_ws, size_t ws_size,
                              hipStream_t stream) {
  const float* z = (const float*)d_in[0];
  const float* cb = (const float*)d_in[1];
  const float* pw = (const float*)d_in[2];
  const float* pb = (const float*)d_in[3];
  // d_in[4] (scale) unused: argmin invariant to positive scale

  float* out0 = (float*)d_out;
  float* out1 = out0 + (size_t)NTOK * DIM;
  float* out2 = out1 + 1;

  hipLaunchKernelGGL(k_codebook, dim3(512), dim3(256), 0, stream, cb, pw, pb);
  hipLaunchKernelGGL(k_znorm, dim3(256), dim3(256), 0, stream, z);
  hipLaunchKernelGGL(k_mfma1, dim3(512), dim3(256), 0, stream);
  hipLaunchKernelGGL(k_mfma2, dim3(512), dim3(256), 0, stream);
  hipLaunchKernelGGL(k_exact, dim3(64), dim3(256), 0, stream, z);
  hipLaunchKernelGGL(k_fullscan, dim3(64), dim3(256), 0, stream, z);
  hipLaunchKernelGGL(k_out, dim3(256), dim3(256), 0, stream, z, out0, out2);
  hipLaunchKernelGGL(k_loss, dim3(1), dim3(1), 0, stream, out1);
}

// Round 8
// 205.725 us; speedup vs baseline: 7.1186x; 1.2192x over previous
//
#include <hip/hip_runtime.h>
#include <hip/hip_bf16.h>

// SimVQ: z[16,1024,64] f32, codebook[16384,64] f32, proj_w[64,64] f32, proj_b[64] f32, scale f32
// Outputs (fp32, concat): quantized_st[1048576], vq_loss[1], idx[16384]
// r8: r6's occupancy (128 tok/block, 4 blocks/CU) + r7's dbuf 1-barrier staging; folded
// threshold compare in pass 2; fused prep (codebook+znorm) and loss finalize (into k_out).
// Margin scheme proven r5-r7: pass1 mfma top value, pass2 collect within 8e-3 (bf16 dot
// err <= 4e-3), fp64 exact arbiter, overflow list -> full scan (normally empty).

#define NCODES 16384
#define NTOK   16384
#define DIM    64
#define MARGIN_MFMA 8e-3f

typedef __attribute__((ext_vector_type(8))) short bf16x8;
typedef __attribute__((ext_vector_type(4))) float f32x4;
#define GLOBAL_AS __attribute__((address_space(1)))
#define LDS_AS    __attribute__((address_space(3)))

__device__ float  g_qcb[NCODES * DIM];   // 4 MB projected codebook fp32 (gather source)
__device__ double g_cn64[NCODES * DIM];  // 8 MB l2norm(qcb) fp64 (exact path)
__device__ short  g_cnb[NCODES * DIM];   // 2 MB l2norm(qcb) bf16 row-major (MFMA B)
__device__ short  g_znb[NTOK * DIM];     // 2 MB l2norm(z)  bf16 row-major (MFMA A)
__device__ unsigned g_topu[NTOK];        // orderable-encoded mfma top-1 value
__device__ int    g_candcnt[NTOK];
__device__ int    g_cand[NTOK * 8];
__device__ int    g_idx[NTOK];
__device__ int    g_ovcnt;               // overflow-token count (expected 0)
__device__ int    g_ovlist[NTOK];
__device__ float  g_loss;
__device__ int    g_done;                // k_out completion counter (loss finalize)

__device__ __forceinline__ float wave_sum64(float v) {
#pragma unroll
  for (int o = 32; o > 0; o >>= 1) v += __shfl_xor(v, o, 64);
  return v;
}
__device__ __forceinline__ double wave_sum64d(double v) {
#pragma unroll
  for (int o = 32; o > 0; o >>= 1) v += __shfl_xor(v, o, 64);
  return v;
}
__device__ __forceinline__ short f2bf(float f) {
  __hip_bfloat16 h = __float2bfloat16(f);
  return *reinterpret_cast<short*>(&h);
}

// Fused prep: blocks [0,512) codebook projection (fp64) ; blocks [512,768) z-normalize +
// per-call state zeroing. Independent outputs, one launch.
__global__ __launch_bounds__(256) void k_prep(const float* __restrict__ cb,
                                              const float* __restrict__ pw,
                                              const float* __restrict__ pb,
                                              const float* __restrict__ z) {
  int tid = threadIdx.x;
  if (blockIdx.x < 512) {
    __shared__ float Wt[64 * 65];   // Wt[k][j] = W[j][k]
    __shared__ float cbs[32 * 65];  // staged cb rows
    int base = blockIdx.x * 32;
    for (int e = tid; e < 4096; e += 256) {
      int j = e >> 6, k = e & 63;
      Wt[k * 65 + j] = pw[e];
    }
    for (int e = tid; e < 2048; e += 256) {
      int row = e >> 6, k = e & 63;
      cbs[row * 65 + k] = cb[(size_t)(base + row) * 64 + k];
    }
    __syncthreads();
    int w = tid >> 6, j = tid & 63;
    double bj = (double)pb[j];
    for (int rr = 0; rr < 8; ++rr) {
      int nl = w * 8 + rr;
      int n = base + nl;
      double acc = bj;
#pragma unroll
      for (int k = 0; k < 64; ++k)
        acc = fma((double)cbs[nl * 65 + k], (double)Wt[k * 65 + j], acc);
      g_qcb[(size_t)n * 64 + j] = (float)acc;
      double tot = wave_sum64d(acc * acc);
      double cn = acc / fmax(sqrt(tot), 1e-12);
      g_cn64[(size_t)n * 64 + j] = cn;
      g_cnb[(size_t)n * 64 + j] = f2bf((float)cn);
    }
  } else {
    int zb = blockIdx.x - 512;  // 256 blocks x 64 tokens
    int gid = zb * 256 + tid;
    if (gid < NTOK) { g_topu[gid] = 0u; g_candcnt[gid] = 0; }
    if (gid == 0) { g_loss = 0.f; g_ovcnt = 0; g_done = 0; }
    int w = tid >> 6, j = tid & 63;
    int base = zb * 64;
    for (int r = 0; r < 16; ++r) {
      int row = base + w * 16 + r;
      float v = z[(size_t)row * 64 + j];
      float tot = wave_sum64(v * v);
      g_znb[(size_t)row * 64 + j] = f2bf(v / fmaxf(sqrtf(tot), 1e-12f));
    }
  }
}

// GEMM core: grid = 128 token-blocks x 8 splits = 1024 blocks (4/CU), 4 waves/block.
// Wave owns 32 tokens (2 A-frag pairs). B double-buffered: 128 codes (16KB)/stage via
// global_load_lds width-16, XOR-swizzled (LDS[row][c] = G[row][c ^ (row&7)]) so B-frag
// ds_read_b128 is 2-way bank-aliased (free). ONE barrier/stage: prefetch s+1 into buf^1
// before computing s (vmcnt drain overlapped with compute).
// MFMA layouts (HW-proven): A m=col,k=quad*8+j ; B n=col,k=quad*8+j ; C/D m=quad*4+reg,n=col.

__global__ __launch_bounds__(256) void k_mfma1() {
  __shared__ __align__(16) short smB[2][8192];  // 2 x 16 KB: 128 codes x 64 shorts
  int tid = threadIdx.x;
  int wave = tid >> 6, lane = tid & 63;
  int quad = lane >> 4, col = lane & 15;
  int tokBlock = blockIdx.x >> 3, split = blockIdx.x & 7;
  int tokBase = tokBlock * 128 + wave * 32;

  const short* za = g_znb + (size_t)(tokBase + col) * 64 + quad * 8;
  bf16x8 A0[2], A1[2];
#pragma unroll
  for (int f = 0; f < 2; ++f) {
    A0[f] = *(const bf16x8*)(za + f * 16 * 64);
    A1[f] = *(const bf16x8*)(za + f * 16 * 64 + 32);
  }
  float m[2][4];
#pragma unroll
  for (int f = 0; f < 2; ++f)
#pragma unroll
    for (int r = 0; r < 4; ++r) m[f][r] = -3.0e38f;

  const char* gsplit = (const char*)(g_cnb + (size_t)split * 2048 * 64);
  int x = col & 7;
  int s0off = ((quad ^ x) << 3);
  int s1off = (((4 | quad) ^ x) << 3);

  int goff[4];
#pragma unroll
  for (int i = 0; i < 4; ++i) {
    int cidx = wave * 256 + i * 64 + lane;
    int row = cidx >> 3, sw = cidx & 7;
    goff[i] = row * 128 + (sw ^ (row & 7)) * 16;
  }

#pragma unroll
  for (int i = 0; i < 4; ++i)
    __builtin_amdgcn_global_load_lds((const GLOBAL_AS void*)(gsplit + goff[i]),
                                     (LDS_AS void*)(&smB[0][wave * 2048 + i * 512]), 16, 0, 0);
  __syncthreads();

  int p = 0;
  for (int s = 0; s < 16; ++s) {
    if (s < 15) {
      const char* gb = gsplit + (size_t)(s + 1) * 16384;
#pragma unroll
      for (int i = 0; i < 4; ++i)
        __builtin_amdgcn_global_load_lds((const GLOBAL_AS void*)(gb + goff[i]),
                                         (LDS_AS void*)(&smB[p ^ 1][wave * 2048 + i * 512]),
                                         16, 0, 0);
    }
    const short* bufp = smB[p];
#pragma unroll
    for (int t = 0; t < 8; ++t) {
      const short* lb = bufp + (t * 16 + col) * 64;
      bf16x8 b0 = *(const bf16x8*)(lb + s0off);
      bf16x8 b1 = *(const bf16x8*)(lb + s1off);
#pragma unroll
      for (int f = 0; f < 2; ++f) {
        f32x4 acc = {0.f, 0.f, 0.f, 0.f};
        acc = __builtin_amdgcn_mfma_f32_16x16x32_bf16(A0[f], b0, acc, 0, 0, 0);
        acc = __builtin_amdgcn_mfma_f32_16x16x32_bf16(A1[f], b1, acc, 0, 0, 0);
#pragma unroll
        for (int r = 0; r < 4; ++r) m[f][r] = fmaxf(m[f][r], acc[r]);
      }
    }
    __syncthreads();  // publishes buf p^1, protects buf p for next prefetch
    p ^= 1;
  }

#pragma unroll
  for (int f = 0; f < 2; ++f)
#pragma unroll
    for (int r = 0; r < 4; ++r) {
      float v = m[f][r];
      v = fmaxf(v, __shfl_xor(v, 1, 64));
      v = fmaxf(v, __shfl_xor(v, 2, 64));
      v = fmaxf(v, __shfl_xor(v, 4, 64));
      v = fmaxf(v, __shfl_xor(v, 8, 64));
      if (col == 0) {
        unsigned b = __float_as_uint(v);
        unsigned e = (b & 0x80000000u) ? ~b : (b | 0x80000000u);
        atomicMax(&g_topu[tokBase + f * 16 + quad * 4 + r], e);
      }
    }
}

__global__ __launch_bounds__(256) void k_mfma2() {
  __shared__ __align__(16) short smB[2][8192];
  int tid = threadIdx.x;
  int wave = tid >> 6, lane = tid & 63;
  int quad = lane >> 4, col = lane & 15;
  int tokBlock = blockIdx.x >> 3, split = blockIdx.x & 7;
  int tokBase = tokBlock * 128 + wave * 32;

  const short* za = g_znb + (size_t)(tokBase + col) * 64 + quad * 8;
  bf16x8 A0[2], A1[2];
#pragma unroll
  for (int f = 0; f < 2; ++f) {
    A0[f] = *(const bf16x8*)(za + f * 16 * 64);
    A1[f] = *(const bf16x8*)(za + f * 16 * 64 + 32);
  }
  float th[2][4];
#pragma unroll
  for (int f = 0; f < 2; ++f)
#pragma unroll
    for (int r = 0; r < 4; ++r) {
      unsigned u = g_topu[tokBase + f * 16 + quad * 4 + r];
      unsigned b = (u & 0x80000000u) ? (u & 0x7FFFFFFFu) : ~u;
      th[f][r] = __uint_as_float(b) - MARGIN_MFMA;
    }

  const char* gsplit = (const char*)(g_cnb + (size_t)split * 2048 * 64);
  int x = col & 7;
  int s0off = ((quad ^ x) << 3);
  int s1off = (((4 | quad) ^ x) << 3);

  int goff[4];
#pragma unroll
  for (int i = 0; i < 4; ++i) {
    int cidx = wave * 256 + i * 64 + lane;
    int row = cidx >> 3, sw = cidx & 7;
    goff[i] = row * 128 + (sw ^ (row & 7)) * 16;
  }

#pragma unroll
  for (int i = 0; i < 4; ++i)
    __builtin_amdgcn_global_load_lds((const GLOBAL_AS void*)(gsplit + goff[i]),
                                     (LDS_AS void*)(&smB[0][wave * 2048 + i * 512]), 16, 0, 0);
  __syncthreads();

  int codeB = split * 2048 + col;
  int p = 0;
  for (int s = 0; s < 16; ++s) {
    if (s < 15) {
      const char* gb = gsplit + (size_t)(s + 1) * 16384;
#pragma unroll
      for (int i = 0; i < 4; ++i)
        __builtin_amdgcn_global_load_lds((const GLOBAL_AS void*)(gb + goff[i]),
                                         (LDS_AS void*)(&smB[p ^ 1][wave * 2048 + i * 512]),
                                         16, 0, 0);
    }
    const short* bufp = smB[p];
#pragma unroll
    for (int t = 0; t < 8; ++t) {
      const short* lb = bufp + (t * 16 + col) * 64;
      bf16x8 b0 = *(const bf16x8*)(lb + s0off);
      bf16x8 b1 = *(const bf16x8*)(lb + s1off);
      int code = codeB + s * 128 + t * 16;
#pragma unroll
      for (int f = 0; f < 2; ++f) {
        f32x4 acc = {0.f, 0.f, 0.f, 0.f};
        acc = __builtin_amdgcn_mfma_f32_16x16x32_bf16(A0[f], b0, acc, 0, 0, 0);
        acc = __builtin_amdgcn_mfma_f32_16x16x32_bf16(A1[f], b1, acc, 0, 0, 0);
        // folded compare: one branch, taken ~never (s_cbranch_execz skips body)
        float dmax = fmaxf(fmaxf(acc[0] - th[f][0], acc[1] - th[f][1]),
                           fmaxf(acc[2] - th[f][2], acc[3] - th[f][3]));
        if (dmax >= 0.f) {
#pragma unroll
          for (int r = 0; r < 4; ++r) {
            if (acc[r] >= th[f][r]) {
              int tok = tokBase + f * 16 + quad * 4 + r;
              int pos = atomicAdd(&g_candcnt[tok], 1);
              if (pos < 8) g_cand[tok * 8 + pos] = code;
            }
          }
        }
      }
    }
    __syncthreads();
    p ^= 1;
  }
}

// Exact fp64 scoring of <=8 candidates per token; overflow -> g_ovlist (expected none).
__global__ __launch_bounds__(256) void k_exact(const float* __restrict__ z) {
  int tok = blockIdx.x * 256 + threadIdx.x;
  if (tok >= NTOK) return;
  int cnt = g_candcnt[tok];
  if (cnt <= 1) { g_idx[tok] = g_cand[tok * 8]; return; }
  if (cnt > 8) {
    int p = atomicAdd(&g_ovcnt, 1);
    g_ovlist[p] = tok;
    return;
  }
  double zr[64];
#pragma unroll
  for (int k = 0; k < 64; ++k) zr[k] = (double)z[(size_t)tok * 64 + k];
  double best = -1.0e300;
  int bi = 0x7FFFFFFF;
  for (int c = 0; c < cnt; ++c) {
    int code = g_cand[tok * 8 + c];
    const double* cr = g_cn64 + (size_t)code * 64;
    double d = 0.0;
#pragma unroll
    for (int k = 0; k < 64; ++k) d = fma(zr[k], cr[k], d);
    if (d > best || (d == best && code < bi)) { best = d; bi = code; }
  }
  g_idx[tok] = bi;
}

// Fallback: full fp64 scan over the overflow list only (normally empty).
__global__ __launch_bounds__(256) void k_fullscan(const float* __restrict__ z) {
  __shared__ double zn[64];
  __shared__ double rb[256];
  __shared__ int ri[256];
  int tid = threadIdx.x;
  int nov = g_ovcnt;
  for (int f = blockIdx.x; f < nov; f += gridDim.x) {
    int tok = g_ovlist[f];
    if (tid < 64) zn[tid] = (double)z[(size_t)tok * 64 + tid];  // unnormalized: scale-invariant
    __syncthreads();
    double best = -1.0e300;
    int bi = 0x7FFFFFFF;
    for (int c = tid; c < NCODES; c += 256) {
      const double* cr = g_cn64 + (size_t)c * 64;
      double d0 = 0.0, d1 = 0.0;
#pragma unroll
      for (int k = 0; k < 64; k += 2) {
        d0 = fma(zn[k], cr[k], d0);
        d1 = fma(zn[k + 1], cr[k + 1], d1);
      }
      double d = d0 + d1;
      if (d > best || (d == best && c < bi)) { best = d; bi = c; }
    }
    rb[tid] = best;
    ri[tid] = bi;
    __syncthreads();
    if (tid == 0) {
      double B = rb[0];
      int I = ri[0];
      for (int xx = 1; xx < 256; ++xx)
        if (rb[xx] > B || (rb[xx] == B && ri[xx] < I)) { B = rb[xx]; I = ri[xx]; }
      g_idx[tok] = I;
    }
    __syncthreads();
  }
}

// Gather + straight-through + loss (finalized by last block via completion counter).
__global__ __launch_bounds__(256) void k_out(const float* __restrict__ z,
                                             float* __restrict__ out0,
                                             float* __restrict__ out1,
                                             float* __restrict__ out2) {
  int tid = threadIdx.x;
  int w = tid >> 6, j = tid & 63;
  int base = blockIdx.x * 64;
  float lsum = 0.f;
  for (int r = 0; r < 16; ++r) {
    int tok = base + w * 16 + r;
    int idx = g_idx[tok];
    float q = g_qcb[(size_t)idx * 64 + j];
    float zv = z[(size_t)tok * 64 + j];
    float d = q - zv;
    out0[(size_t)tok * 64 + j] = zv + d;  // z + (q - z), ref op order
    lsum = fmaf(d, d, lsum);
    if (j == 0) out2[tok] = (float)idx;
  }
  float tot = wave_sum64(lsum);
  if (j == 0) atomicAdd(&g_loss, tot);
  __syncthreads();
  if (tid == 0) {
    __threadfence();
    int d = atomicAdd(&g_done, 1);
    if (d == (int)gridDim.x - 1) {
      __threadfence();
      float lv = atomicAdd(&g_loss, 0.0f);  // atomic read-after-all-adds
      out1[0] = 1.25f * lv / 1048576.0f;    // commitment == codebook numerically
    }
  }
}

extern "C" void kernel_launch(void* const* d_in, const int* in_sizes, int n_in,
                              void* d_out, int out_size, void* d_ws, size_t ws_size,
                              hipStream_t stream) {
  const float* z = (const float*)d_in[0];
  const float* cb = (const float*)d_in[1];
  const float* pw = (const float*)d_in[2];
  const float* pb = (const float*)d_in[3];
  // d_in[4] (scale) unused: argmin invariant to positive scale

  float* out0 = (float*)d_out;
  float* out1 = out0 + (size_t)NTOK * DIM;
  float* out2 = out1 + 1;

  hipLaunchKernelGGL(k_prep, dim3(768), dim3(256), 0, stream, cb, pw, pb, z);
  hipLaunchKernelGGL(k_mfma1, dim3(1024), dim3(256), 0, stream);
  hipLaunchKernelGGL(k_mfma2, dim3(1024), dim3(256), 0, stream);
  hipLaunchKernelGGL(k_exact, dim3(64), dim3(256), 0, stream, z);
  hipLaunchKernelGGL(k_fullscan, dim3(64), dim3(256), 0, stream, z);
  hipLaunchKernelGGL(k_out, dim3(256), dim3(256), 0, stream, z, out0, out1, out2);
}